// Round 6
// baseline (446.302 us; speedup 1.0000x reference)
//
#include <hip/hip_runtime.h>
#include <math.h>

// Problem constants (fixed by reference)
#define BB   16
#define LATD 8
#define NN   500000
#define XSZ  256
#define HALF 128
#define IMG_ELEMS (BB * XSZ * XSZ)          // 1,048,576 pixels
#define FREQ_COLS 129                        // XS/2+1
#define NBLK ((NN + 255) / 256)              // 1954 point-blocks

// Fixed-point accumulate: q = rint(v * 2^14). Native int atomics (global
// and LDS) are single-instruction fire-and-forget on gfx950; float
// atomicAdd compiles to a CAS retry loop (no -munsafe-fp-atomics) which
// pinned every accumulate variant at ~67us (R0-R3, fixed in R4). Direct
// global int scatter (R6) removes the whole bucket sort: the sort existed
// only to avoid global float CAS atomics. Sums: ~8 entries/pixel avg,
// |q| < 2^20 -> total well inside int32.
#define QSCALE 16384.0f
#define QINV   (1.0f / 16384.0f)

// ---------------------------------------------------------------------------
// K0: per-image prep — rotation rows 0/1, shifts+half, SIREN MLP hidden h[8]
// ---------------------------------------------------------------------------
__global__ void prep_kernel(const float* __restrict__ rows,
                            const float* __restrict__ shifts,
                            const float* __restrict__ latent,
                            const float* __restrict__ W0, const float* __restrict__ b0,
                            const float* __restrict__ W1, const float* __restrict__ b1,
                            const float* __restrict__ W2, const float* __restrict__ b2,
                            const float* __restrict__ W3, const float* __restrict__ b3,
                            float* __restrict__ bdata) {
    int b = threadIdx.x;
    if (b >= BB) return;

    float rot  = rows[b * 3 + 0];
    float tilt = rows[b * 3 + 1];
    float psi  = rows[b * 3 + 2];
    float ca, sa, cb, sb, cg, sg;
    sincosf(rot, &sa, &ca);
    sincosf(tilt, &sb, &cb);
    sincosf(psi, &sg, &cg);

    float R00 =  cg * cb * ca - sg * sa;
    float R01 =  cg * cb * sa + sg * ca;
    float R02 = -cg * sb;
    float R10 = -sg * cb * ca - cg * sa;
    float R11 = -sg * cb * sa + cg * ca;
    float R12 =  sg * sb;

    float h[LATD], t[LATD];
    #pragma unroll
    for (int j = 0; j < LATD; ++j) {
        float acc = b0[j];
        #pragma unroll
        for (int l = 0; l < LATD; ++l) acc += latent[b * LATD + l] * W0[l * LATD + j];
        t[j] = acc;
    }
    #pragma unroll
    for (int j = 0; j < LATD; ++j) h[j] = sinf(30.0f * t[j]);

    const float* Ws[3] = {W1, W2, W3};
    const float* bs[3] = {b1, b2, b3};
    for (int L = 0; L < 3; ++L) {
        #pragma unroll
        for (int j = 0; j < LATD; ++j) {
            float acc = bs[L][j];
            #pragma unroll
            for (int l = 0; l < LATD; ++l) acc += h[l] * Ws[L][l * LATD + j];
            t[j] = acc;
        }
        #pragma unroll
        for (int j = 0; j < LATD; ++j) h[j] += sinf(t[j]);
    }

    float* P = bdata + b * 16;
    P[0] = R00; P[1] = R01; P[2] = R02;
    P[3] = R10; P[4] = R11; P[5] = R12;
    P[6] = shifts[b * 2 + 0] + (float)HALF;
    P[7] = shifts[b * 2 + 1] + (float)HALF;
    #pragma unroll
    for (int j = 0; j < LATD; ++j) P[8 + j] = h[j];
}

__device__ __forceinline__ int2 project_px(const float* __restrict__ Q,
                                           float cx, float cy, float cz) {
    float x = fmaf(Q[0], cx, fmaf(Q[1], cy, fmaf(Q[2], cz, Q[6])));
    float y = fmaf(Q[3], cx, fmaf(Q[4], cy, fmaf(Q[5], cz, Q[7])));
    float px = fminf(fmaxf(rintf(x), 0.f), 255.f);
    float py = fminf(fmaxf(rintf(y), 0.f), 255.f);
    return make_int2((int)px, (int)py);
}

// ---------------------------------------------------------------------------
// K1: zero the quantized image (uint4 stores, 4 MB)
// ---------------------------------------------------------------------------
__global__ __launch_bounds__(256) void zero_q_kernel(uint4* __restrict__ p) {
    int i = blockIdx.x * 256 + threadIdx.x;
    p[i] = make_uint4(0u, 0u, 0u, 0u);
}

// ---------------------------------------------------------------------------
// K2: scatter_q — per point, per image: project, MLP delta, quantize,
// ONE native global int atomic into the L2-resident 4 MB imgq.
// ---------------------------------------------------------------------------
__global__ __launch_bounds__(256) void scatter_q_kernel(
        const float* __restrict__ coords, const float* __restrict__ values,
        const float* __restrict__ Wd, const float* __restrict__ bd,
        const float* __restrict__ bdata, unsigned* __restrict__ imgq) {
    __shared__ float P[256];
    P[threadIdx.x] = bdata[threadIdx.x];
    __syncthreads();
    int n = blockIdx.x * 256 + threadIdx.x;
    if (n >= NN) return;
    float cx = coords[n * 3 + 0];
    float cy = coords[n * 3 + 1];
    float cz = coords[n * 3 + 2];
    float base = values[n] + bd[n];
    float wd[LATD];
    #pragma unroll
    for (int l = 0; l < LATD; ++l) wd[l] = Wd[l * NN + n];
    #pragma unroll
    for (int b = 0; b < BB; ++b) {
        const float* Q = &P[b * 16];
        int2 p = project_px(Q, cx, cy, cz);
        float delta = 0.f;
        #pragma unroll
        for (int l = 0; l < LATD; ++l) delta = fmaf(Q[8 + l], wd[l], delta);
        int q = (int)rintf((base + delta) * QSCALE);
        atomicAdd(&imgq[(b << 16) | (p.y << 8) | p.x], (unsigned)q);
    }
}

// ---------------------------------------------------------------------------
// Gaussian 7-tap weights (sigma=1, radius=3, normalized)
// ---------------------------------------------------------------------------
__device__ __constant__ float GW[4] = {0.39905027f, 0.24203623f, 0.05400558f, 0.00443305f};

// ---------------------------------------------------------------------------
// 256-point complex Stockham FFT in LDS, one 64-lane slice per FFT.
// ---------------------------------------------------------------------------
__device__ __forceinline__ void fft256(float2* src, float2* dst,
                                       const float2* __restrict__ TW,
                                       int lane, float dir) {
    #pragma unroll
    for (int t = 0; t < 8; ++t) {
        const int s = 1 << t;
        #pragma unroll
        for (int r = 0; r < 2; ++r) {
            int i = lane + (r << 6);
            int q = i & (s - 1);
            int p = i >> t;
            float2 a = src[q + s * p];
            float2 b = src[q + s * p + 128];
            int m = p << t;
            float cs = TW[m].x;
            float sn = dir * TW[m].y;
            float2 sum = make_float2(a.x + b.x, a.y + b.y);
            float dx = a.x - b.x;
            float dy = a.y - b.y;
            float2 tw = make_float2(dx * cs - dy * sn, dx * sn + dy * cs);
            int o = q + ((p * s) << 1);
            dst[o] = sum;
            dst[o + s] = tw;
        }
        __syncthreads();
        float2* tmp = src; src = dst; dst = tmp;
    }
}

__device__ __forceinline__ void fill_tw256(float2* TW, int tid) {
    if (tid < 128) {
        float sn, cs;
        sincosf(0.0245436926061703f * (float)tid, &sn, &cs);
        TW[tid] = make_float2(cs, sn);
    }
}

// ---------------------------------------------------------------------------
// K3: dequantize + x-blur + forward row rFFT, 4 rows per block.
// ---------------------------------------------------------------------------
__global__ __launch_bounds__(256) void fft_rows_fwd(const unsigned* __restrict__ imgq,
                                                    float2* __restrict__ Freq) {
    __shared__ float2 bufA[4][256];
    __shared__ float2 bufB[4][256];
    __shared__ float2 TW[128];
    __shared__ float  rowr[4][256];
    int tid = threadIdx.x;
    int lane = tid & 63;
    int sub = tid >> 6;
    fill_tw256(TW, tid);
    int b  = blockIdx.x >> 6;
    int y0 = (blockIdx.x & 63) << 2;

    const unsigned* src = imgq + (((size_t)(b << 8) + y0) << 8);
    for (int i = tid; i < 1024; i += 256) {
        ((float*)rowr)[i] = (float)(int)src[i] * QINV;
    }
    __syncthreads();

    #pragma unroll
    for (int j = 0; j < 4; ++j) {
        int x = lane + (j << 6);
        float acc = GW[0] * rowr[sub][x];
        #pragma unroll
        for (int t = 1; t <= 3; ++t) {
            if (x - t >= 0)  acc += GW[t] * rowr[sub][x - t];
            if (x + t < 256) acc += GW[t] * rowr[sub][x + t];
        }
        bufA[sub][x] = make_float2(acc, 0.f);
    }
    __syncthreads();
    fft256(bufA[sub], bufB[sub], TW, lane, -1.f);

    for (int i = tid; i < FREQ_COLS * 4; i += 256) {
        int col = i >> 2;
        int s   = i & 3;
        Freq[((size_t)(b * FREQ_COLS + col) << 8) + y0 + s] = bufA[s][col];
    }
}

// ---------------------------------------------------------------------------
// K4: column pass — y-blur (complex) + FFT + CTF + inverse FFT, 4 cols/block.
// ---------------------------------------------------------------------------
__global__ __launch_bounds__(256) void fft_cols_ctf(float2* __restrict__ Freq,
                                                    const float* __restrict__ ctf) {
    __shared__ float2 bufA[4][256];
    __shared__ float2 bufB[4][256];
    __shared__ float2 TW[128];
    int tid = threadIdx.x;
    int lane = tid & 63;
    int sub = tid >> 6;
    fill_tw256(TW, tid);
    int b  = blockIdx.x / 33;
    int c0 = (blockIdx.x - b * 33) << 2;
    int col  = c0 + sub;
    int colc = col < FREQ_COLS ? col : (FREQ_COLS - 1);
    float2* basep = Freq + ((size_t)(b * FREQ_COLS + colc) << 8);

    #pragma unroll
    for (int j = 0; j < 4; ++j) {
        int k = lane + (j << 6);
        bufB[sub][k] = basep[k];
    }
    __syncthreads();
    #pragma unroll
    for (int j = 0; j < 4; ++j) {
        int k = lane + (j << 6);
        float ax = GW[0] * bufB[sub][k].x;
        float ay = GW[0] * bufB[sub][k].y;
        #pragma unroll
        for (int t = 1; t <= 3; ++t) {
            if (k - t >= 0)  { ax += GW[t] * bufB[sub][k - t].x; ay += GW[t] * bufB[sub][k - t].y; }
            if (k + t < 256) { ax += GW[t] * bufB[sub][k + t].x; ay += GW[t] * bufB[sub][k + t].y; }
        }
        bufA[sub][k] = make_float2(ax, ay);
    }
    __syncthreads();
    fft256(bufA[sub], bufB[sub], TW, lane, -1.f);
    #pragma unroll
    for (int j = 0; j < 4; ++j) {
        int k = lane + (j << 6);
        float c = ctf[(size_t)((b << 8) | k) * FREQ_COLS + colc];
        bufA[sub][k].x *= c;
        bufA[sub][k].y *= c;
    }
    __syncthreads();
    fft256(bufA[sub], bufB[sub], TW, lane, +1.f);
    if (col < FREQ_COLS) {
        #pragma unroll
        for (int j = 0; j < 4; ++j) {
            int k = lane + (j << 6);
            basep[k] = bufA[sub][k];
        }
    }
}

// ---------------------------------------------------------------------------
// K5: Hermitian-extend + inverse row FFT + scale, 4 rows per block.
// ---------------------------------------------------------------------------
__global__ __launch_bounds__(256) void fft_rows_inv(const float2* __restrict__ Freq,
                                                    float* __restrict__ out) {
    __shared__ float2 bufA[4][256];
    __shared__ float2 bufB[4][256];
    __shared__ float2 TW[128];
    int tid = threadIdx.x;
    int lane = tid & 63;
    int sub = tid >> 6;
    fill_tw256(TW, tid);
    int b  = blockIdx.x >> 6;
    int y0 = (blockIdx.x & 63) << 2;

    for (int i = tid; i < FREQ_COLS * 4; i += 256) {
        int col = i >> 2;
        int s   = i & 3;
        bufA[s][col] = Freq[((size_t)(b * FREQ_COLS + col) << 8) + y0 + s];
    }
    __syncthreads();
    for (int k = FREQ_COLS + lane; k < 256; k += 64) {
        float2 v = bufA[sub][256 - k];
        bufA[sub][k] = make_float2(v.x, -v.y);
    }
    __syncthreads();
    fft256(bufA[sub], bufB[sub], TW, lane, +1.f);
    float* dst = out + (((size_t)(b << 8) + y0) << 8);
    const float scale = 1.0f / 65536.0f;
    for (int i = tid; i < 1024; i += 256) {
        dst[i] = bufA[i >> 8][i & 255].x * scale;
    }
}

// ---------------------------------------------------------------------------
extern "C" void kernel_launch(void* const* d_in, const int* in_sizes, int n_in,
                              void* d_out, int out_size, void* d_ws, size_t ws_size,
                              hipStream_t stream) {
    const float* rows   = (const float*)d_in[0];
    const float* shifts = (const float*)d_in[1];
    const float* latent = (const float*)d_in[2];
    const float* coords = (const float*)d_in[3];
    const float* values = (const float*)d_in[4];
    const float* W0     = (const float*)d_in[5];
    const float* b0     = (const float*)d_in[6];
    const float* W1     = (const float*)d_in[7];
    const float* b1     = (const float*)d_in[8];
    const float* W2     = (const float*)d_in[9];
    const float* b2     = (const float*)d_in[10];
    const float* W3     = (const float*)d_in[11];
    const float* b3     = (const float*)d_in[12];
    const float* Wd     = (const float*)d_in[13];
    const float* bd     = (const float*)d_in[14];
    const float* ctf    = (const float*)d_in[15];
    float* out = (float*)d_out;

    // Workspace layout (tiny now: ~8.5 MB)
    char* w = (char*)d_ws;
    size_t off = 0;
    float* bdata    = (float*)(w + off);    off += 4096;
    unsigned* imgq  = (unsigned*)(w + off); off += (size_t)IMG_ELEMS * 4;          // 4 MB
    float2* Freq    = (float2*)(w + off);   off += (size_t)BB * FREQ_COLS * 256 * 8; // 4.2 MB

    prep_kernel<<<1, 64, 0, stream>>>(rows, shifts, latent,
                                      W0, b0, W1, b1, W2, b2, W3, b3, bdata);

    zero_q_kernel<<<IMG_ELEMS / 4 / 256, 256, 0, stream>>>((uint4*)imgq);

    scatter_q_kernel<<<NBLK, 256, 0, stream>>>(coords, values, Wd, bd, bdata, imgq);

    fft_rows_fwd<<<BB * 64, 256, 0, stream>>>(imgq, Freq);
    fft_cols_ctf<<<BB * 33, 256, 0, stream>>>(Freq, ctf);
    fft_rows_inv<<<BB * 64, 256, 0, stream>>>(Freq, out);
}

// Round 7
// 168.120 us; speedup vs baseline: 2.6547x; 2.6547x over previous
//
#include <hip/hip_runtime.h>
#include <math.h>

// Problem constants (fixed by reference)
#define BB   16
#define LATD 8
#define NN   500000
#define XSZ  256
#define HALF 128
#define IMG_ELEMS (BB * XSZ * XSZ)          // 1,048,576 pixels
#define FREQ_COLS 129                        // XS/2+1
#define NBLK ((NN + 255) / 256)              // 1954 point-blocks

// Entry packing: bits[11:0] = pixel-in-tile, bits[31:12] = SIGNED 20-bit
// fixed-point value, scale 2^14. Native int LDS atomics (ds_add_u32)
// accumulate exactly; float atomicAdd = CAS retry loop (~67us pin, R0-R3).
// Global int atomics are memory-side on MI355X (non-coherent per-XCD L2):
// 8M of them wrote 249MB to HBM = 320us (R6). LDS-only atomics + the
// block-local bucket sort is the right structure.
#define QSCALE 16384.0f
#define QINV   (1.0f / 16384.0f)
__device__ __forceinline__ unsigned pack_entry_q(float v, int off12) {
    int q = (int)rintf(v * QSCALE);
    q = q >  524287 ?  524287 : q;
    q = q < -524288 ? -524288 : q;
    return ((unsigned)q << 12) | (unsigned)off12;
}
__device__ __forceinline__ int entry_q(unsigned e) {
    return ((int)e) >> 12;     // arithmetic shift: sign-extended 20-bit value
}

// ---------------------------------------------------------------------------
// wave64 inclusive scan (shuffle-based, no barriers)
// ---------------------------------------------------------------------------
__device__ __forceinline__ unsigned wave_incl_scan(unsigned x, int lane) {
    #pragma unroll
    for (int d = 1; d < 64; d <<= 1) {
        unsigned y = __shfl_up(x, d, 64);
        if (lane >= d) x += y;
    }
    return x;
}

// ---------------------------------------------------------------------------
// K0: per-image prep — rotation rows 0/1, shifts+half, SIREN MLP hidden h[8]
// ---------------------------------------------------------------------------
__global__ void prep_kernel(const float* __restrict__ rows,
                            const float* __restrict__ shifts,
                            const float* __restrict__ latent,
                            const float* __restrict__ W0, const float* __restrict__ b0,
                            const float* __restrict__ W1, const float* __restrict__ b1,
                            const float* __restrict__ W2, const float* __restrict__ b2,
                            const float* __restrict__ W3, const float* __restrict__ b3,
                            float* __restrict__ bdata) {
    int b = threadIdx.x;
    if (b >= BB) return;

    float rot  = rows[b * 3 + 0];
    float tilt = rows[b * 3 + 1];
    float psi  = rows[b * 3 + 2];
    float ca, sa, cb, sb, cg, sg;
    sincosf(rot, &sa, &ca);
    sincosf(tilt, &sb, &cb);
    sincosf(psi, &sg, &cg);

    float R00 =  cg * cb * ca - sg * sa;
    float R01 =  cg * cb * sa + sg * ca;
    float R02 = -cg * sb;
    float R10 = -sg * cb * ca - cg * sa;
    float R11 = -sg * cb * sa + cg * ca;
    float R12 =  sg * sb;

    float h[LATD], t[LATD];
    #pragma unroll
    for (int j = 0; j < LATD; ++j) {
        float acc = b0[j];
        #pragma unroll
        for (int l = 0; l < LATD; ++l) acc += latent[b * LATD + l] * W0[l * LATD + j];
        t[j] = acc;
    }
    #pragma unroll
    for (int j = 0; j < LATD; ++j) h[j] = sinf(30.0f * t[j]);

    const float* Ws[3] = {W1, W2, W3};
    const float* bs[3] = {b1, b2, b3};
    for (int L = 0; L < 3; ++L) {
        #pragma unroll
        for (int j = 0; j < LATD; ++j) {
            float acc = bs[L][j];
            #pragma unroll
            for (int l = 0; l < LATD; ++l) acc += h[l] * Ws[L][l * LATD + j];
            t[j] = acc;
        }
        #pragma unroll
        for (int j = 0; j < LATD; ++j) h[j] += sinf(t[j]);
    }

    float* P = bdata + b * 16;
    P[0] = R00; P[1] = R01; P[2] = R02;
    P[3] = R10; P[4] = R11; P[5] = R12;
    P[6] = shifts[b * 2 + 0] + (float)HALF;
    P[7] = shifts[b * 2 + 1] + (float)HALF;
    #pragma unroll
    for (int j = 0; j < LATD; ++j) P[8 + j] = h[j];
}

__device__ __forceinline__ int2 project_px(const float* __restrict__ Q,
                                           float cx, float cy, float cz) {
    float x = fmaf(Q[0], cx, fmaf(Q[1], cy, fmaf(Q[2], cz, Q[6])));
    float y = fmaf(Q[3], cx, fmaf(Q[4], cy, fmaf(Q[5], cz, Q[7])));
    float px = fminf(fmaxf(rintf(x), 0.f), 255.f);
    float py = fminf(fmaxf(rintf(y), 0.f), 255.f);
    return make_int2((int)px, (int)py);
}

// ---------------------------------------------------------------------------
// K1: fill3 — LDS-atomic ranking, per-block output: tile-sorted contiguous
// 4096-entry segment + lbaseT[blk][257] offset row. R7 change: the ranking
// loop STAGGERS the image index per 16-thread group (bi = (tid>>4 + i)&15)
// so one wave's 64 lanes hit 4 images x 16 tiles = 64 distinct hist
// counters instead of 16 (-> ~1 lane/bucket, was ~4-way same-address
// serialization on ds_add_rtn). Arrays indexed by loop var i (static),
// not bi, to avoid scratch (runtime-indexed reg arrays spill).
// ---------------------------------------------------------------------------
__global__ __launch_bounds__(256) void fill3_kernel(
        const float* __restrict__ coords, const float* __restrict__ values,
        const float* __restrict__ Wd, const float* __restrict__ bd,
        const float* __restrict__ bdata, unsigned* __restrict__ bucket,
        unsigned* __restrict__ lbaseT) {
    __shared__ float    P[256];
    __shared__ unsigned hist[256];
    __shared__ unsigned wsum[4];
    __shared__ unsigned lbase[256];
    __shared__ unsigned stage[4096];

    int tid = threadIdx.x;
    int blk = blockIdx.x;
    int lane = tid & 63;
    int w = tid >> 6;
    int grp = tid >> 4;          // 16-thread group id (stagger phase)
    P[tid] = bdata[tid];
    hist[tid] = 0;
    __syncthreads();

    int n = blk * 256 + tid;
    bool active = (n < NN);

    unsigned word[BB];
    unsigned rk[BB];
    unsigned char tl[BB];
    if (active) {
        float cx = coords[n * 3 + 0];
        float cy = coords[n * 3 + 1];
        float cz = coords[n * 3 + 2];
        float base = values[n] + bd[n];
        float wd[LATD];
        #pragma unroll
        for (int l = 0; l < LATD; ++l) wd[l] = Wd[l * NN + n];
        #pragma unroll
        for (int i = 0; i < BB; ++i) {
            int bi = (grp + i) & 15;                 // staggered image index
            const float* Q = &P[bi * 16];
            int2 p = project_px(Q, cx, cy, cz);
            float delta = 0.f;
            #pragma unroll
            for (int l = 0; l < LATD; ++l) delta = fmaf(Q[8 + l], wd[l], delta);
            int tile = bi * 16 + (p.y >> 4);
            int off12 = ((p.y & 15) << 8) | p.x;
            word[i] = pack_entry_q(base + delta, off12);
            tl[i] = (unsigned char)tile;
            rk[i] = atomicAdd(&hist[tile], 1u);
        }
    }
    __syncthreads();

    // exclusive scan of hist (256 counters) via wave shuffles
    unsigned v = hist[tid];
    unsigned s = wave_incl_scan(v, lane);
    if (lane == 63) wsum[w] = s;
    __syncthreads();
    unsigned off = 0;
    #pragma unroll
    for (int i = 0; i < 4; ++i) { unsigned u = wsum[i]; if (i < w) off += u; }
    unsigned excl = s + off - v;
    lbase[tid] = excl;
    __syncthreads();

    if (active) {
        #pragma unroll
        for (int i = 0; i < BB; ++i) {
            stage[lbase[tl[i]] + rk[i]] = word[i];
        }
    }

    int nactive = NN - blk * 256;
    if (nactive > 256) nactive = 256;
    int tot = nactive * BB;

    // offset row (coalesced): lbaseT[blk][t] = run start, [blk][256] = total
    lbaseT[(size_t)blk * 257 + tid] = excl;
    if (tid == 0) lbaseT[(size_t)blk * 257 + 256] = (unsigned)tot;
    __syncthreads();

    unsigned* seg = bucket + ((size_t)blk << 12);
    for (int i = tid; i < tot; i += 256) seg[i] = stage[i];
}

// ---------------------------------------------------------------------------
// K2: accum2b — block (t,m) accumulates tile t over a slice of source
// blocks. Bounds prefetched to LDS, 4 runs/wave, 3-deep chunk pipeline,
// 3 exec-masked slots covering runs <=48. INT fixed-point LDS atomics
// (native ds_add_u32); writeout converts to float once.
// ---------------------------------------------------------------------------
#define ACC_ISSUE(cc, S, E, Bs, X0, X1, X2) do {                            \
    int r_ = ((cc) << 4) + (w << 2) + g;                                    \
    S = 0u; E = 0u;                                                         \
    if ((cc) < nChunks && r_ < nB) { S = sArr[r_]; E = eArr[r_]; }          \
    Bs = ((size_t)(blk0 + r_) << 12);                                       \
    unsigned i0_ = S + (unsigned)sl;                                        \
    X0 = (i0_        < E) ? bucket[Bs + i0_]        : 0u;                   \
    X1 = (i0_ + 16u  < E) ? bucket[Bs + i0_ + 16u]  : 0u;                   \
    X2 = (i0_ + 32u  < E) ? bucket[Bs + i0_ + 32u]  : 0u;                   \
} while (0)

#define ACC_PROC(S, E, Bs, X0, X1, X2) do {                                 \
    unsigned i0_ = S + (unsigned)sl;                                        \
    if (i0_       < E) atomicAdd(&tile[X0 & 4095u], (unsigned)entry_q(X0)); \
    if (i0_ + 16u < E) atomicAdd(&tile[X1 & 4095u], (unsigned)entry_q(X1)); \
    if (i0_ + 32u < E) atomicAdd(&tile[X2 & 4095u], (unsigned)entry_q(X2)); \
    for (unsigned i_ = i0_ + 48u; i_ < E; i_ += 16u) {                      \
        unsigned x_ = bucket[Bs + i_];                                      \
        atomicAdd(&tile[x_ & 4095u], (unsigned)entry_q(x_));                \
    }                                                                       \
} while (0)

__global__ __launch_bounds__(256) void accum2b_kernel(
        const unsigned* __restrict__ bucket, const unsigned* __restrict__ lbaseT,
        float* __restrict__ partials, int M) {
    __shared__ unsigned tile[4096];
    __shared__ unsigned sArr[1024];   // sized for M=2 worst case (nB<=977)
    __shared__ unsigned eArr[1024];
    int t = blockIdx.x & 255;
    int m = blockIdx.x >> 8;
    int tid = threadIdx.x;
    int lane = tid & 63;
    int w = tid >> 6;
    #pragma unroll
    for (int i = 0; i < 16; ++i) tile[tid + (i << 8)] = 0u;

    int blk0 = (int)((long long)NBLK * m / M);
    int blk1 = (int)((long long)NBLK * (m + 1) / M);
    int nB = blk1 - blk0;

    // Prefetch run bounds for every source block in the slice (independent
    // loads, fully parallel; lbaseT is hot in L2 after the first readers).
    for (int r = tid; r < nB; r += 256) {
        const unsigned* lrow = lbaseT + (size_t)(blk0 + r) * 257;
        sArr[r] = lrow[t];
        eArr[r] = lrow[t + 1];   // t=255 -> slot 256 = total
    }
    __syncthreads();

    int g  = (lane >> 4);        // run group within wave: 0..3
    int sl = lane & 15;          // slot within run
    int nChunks = (nB + 15) >> 4;

    unsigned sA, eA, xA0, xA1, xA2; size_t bA;
    unsigned sB, eB, xB0, xB1, xB2; size_t bB;
    unsigned sC, eC, xC0, xC1, xC2; size_t bC;

    ACC_ISSUE(0, sA, eA, bA, xA0, xA1, xA2);
    ACC_ISSUE(1, sB, eB, bB, xB0, xB1, xB2);
    for (int c = 0; c < nChunks; c += 3) {
        ACC_ISSUE(c + 2, sC, eC, bC, xC0, xC1, xC2);
        ACC_PROC(sA, eA, bA, xA0, xA1, xA2);
        ACC_ISSUE(c + 3, sA, eA, bA, xA0, xA1, xA2);
        ACC_PROC(sB, eB, bB, xB0, xB1, xB2);
        ACC_ISSUE(c + 4, sB, eB, bB, xB0, xB1, xB2);
        ACC_PROC(sC, eC, bC, xC0, xC1, xC2);
    }
    __syncthreads();
    float* dst = partials + (((size_t)m * 256 + t) << 12);
    for (int k = tid; k < 4096; k += 256) {
        dst[k] = (float)(int)tile[k] * QINV;
    }
}

// ---------------------------------------------------------------------------
// Fallback: device-scope atomic scatter (R1 path) + zero
// ---------------------------------------------------------------------------
__global__ void zero_kernel(float4* __restrict__ p, int n4) {
    int i = blockIdx.x * blockDim.x + threadIdx.x;
    if (i < n4) p[i] = make_float4(0.f, 0.f, 0.f, 0.f);
}

__global__ __launch_bounds__(256) void scatter_atomic_kernel(
        const float* __restrict__ coords, const float* __restrict__ values,
        const float* __restrict__ Wd, const float* __restrict__ bd,
        const float* __restrict__ bdata, float* __restrict__ img) {
    __shared__ float P[BB * 16];
    P[threadIdx.x] = bdata[threadIdx.x];
    __syncthreads();
    int n = blockIdx.x * 256 + threadIdx.x;
    if (n >= NN) return;
    float cx = coords[n * 3 + 0];
    float cy = coords[n * 3 + 1];
    float cz = coords[n * 3 + 2];
    float base = values[n] + bd[n];
    float wd[LATD];
    #pragma unroll
    for (int l = 0; l < LATD; ++l) wd[l] = Wd[l * NN + n];
    #pragma unroll
    for (int b = 0; b < BB; ++b) {
        const float* Q = &P[b * 16];
        int2 p = project_px(Q, cx, cy, cz);
        float delta = 0.f;
        #pragma unroll
        for (int l = 0; l < LATD; ++l) delta = fmaf(Q[8 + l], wd[l], delta);
        atomicAdd(img + ((b << 16) | (p.y << 8) | p.x), base + delta);
    }
}

// ---------------------------------------------------------------------------
// Gaussian 7-tap weights (sigma=1, radius=3, normalized)
// ---------------------------------------------------------------------------
__device__ __constant__ float GW[4] = {0.39905027f, 0.24203623f, 0.05400558f, 0.00443305f};

// ---------------------------------------------------------------------------
// 256-point complex Stockham FFT in LDS, one 64-lane slice per FFT.
// ---------------------------------------------------------------------------
__device__ __forceinline__ void fft256(float2* src, float2* dst,
                                       const float2* __restrict__ TW,
                                       int lane, float dir) {
    #pragma unroll
    for (int t = 0; t < 8; ++t) {
        const int s = 1 << t;
        #pragma unroll
        for (int r = 0; r < 2; ++r) {
            int i = lane + (r << 6);
            int q = i & (s - 1);
            int p = i >> t;
            float2 a = src[q + s * p];
            float2 b = src[q + s * p + 128];
            int m = p << t;
            float cs = TW[m].x;
            float sn = dir * TW[m].y;
            float2 sum = make_float2(a.x + b.x, a.y + b.y);
            float dx = a.x - b.x;
            float dy = a.y - b.y;
            float2 tw = make_float2(dx * cs - dy * sn, dx * sn + dy * cs);
            int o = q + ((p * s) << 1);
            dst[o] = sum;
            dst[o + s] = tw;
        }
        __syncthreads();
        float2* tmp = src; src = dst; dst = tmp;
    }
}

__device__ __forceinline__ void fill_tw256(float2* TW, int tid) {
    if (tid < 128) {
        float sn, cs;
        sincosf(0.0245436926061703f * (float)tid, &sn, &cs);
        TW[tid] = make_float2(cs, sn);
    }
}

// ---------------------------------------------------------------------------
// K3: (sum M partials) + x-blur + forward row rFFT, 4 rows per block.
// ---------------------------------------------------------------------------
__global__ __launch_bounds__(256) void fft_rows_fwd(const float* __restrict__ img,
                                                    const float* __restrict__ partials,
                                                    int M,
                                                    float2* __restrict__ Freq) {
    __shared__ float2 bufA[4][256];
    __shared__ float2 bufB[4][256];
    __shared__ float2 TW[128];
    __shared__ float  rowr[4][256];
    int tid = threadIdx.x;
    int lane = tid & 63;
    int sub = tid >> 6;
    fill_tw256(TW, tid);
    int b  = blockIdx.x >> 6;
    int y0 = (blockIdx.x & 63) << 2;

    if (M > 0) {
        int t = (b << 4) | (y0 >> 4);
        const float* pb = partials + ((size_t)t << 12) + ((y0 & 15) << 8);
        const size_t mstr = (size_t)256 << 12;
        for (int i = tid; i < 1024; i += 256) {
            float s = 0.f;
            for (int m = 0; m < M; ++m) s += pb[(size_t)m * mstr + i];
            ((float*)rowr)[i] = s;
        }
    } else {
        const float* src = img + (((size_t)(b << 8) + y0) << 8);
        for (int i = tid; i < 1024; i += 256) ((float*)rowr)[i] = src[i];
    }
    __syncthreads();

    #pragma unroll
    for (int j = 0; j < 4; ++j) {
        int x = lane + (j << 6);
        float acc = GW[0] * rowr[sub][x];
        #pragma unroll
        for (int t = 1; t <= 3; ++t) {
            if (x - t >= 0)  acc += GW[t] * rowr[sub][x - t];
            if (x + t < 256) acc += GW[t] * rowr[sub][x + t];
        }
        bufA[sub][x] = make_float2(acc, 0.f);
    }
    __syncthreads();
    fft256(bufA[sub], bufB[sub], TW, lane, -1.f);

    for (int i = tid; i < FREQ_COLS * 4; i += 256) {
        int col = i >> 2;
        int s   = i & 3;
        Freq[((size_t)(b * FREQ_COLS + col) << 8) + y0 + s] = bufA[s][col];
    }
}

// ---------------------------------------------------------------------------
// K4: column pass — y-blur (complex) + FFT + CTF + inverse FFT, 4 cols/block.
// ---------------------------------------------------------------------------
__global__ __launch_bounds__(256) void fft_cols_ctf(float2* __restrict__ Freq,
                                                    const float* __restrict__ ctf) {
    __shared__ float2 bufA[4][256];
    __shared__ float2 bufB[4][256];
    __shared__ float2 TW[128];
    int tid = threadIdx.x;
    int lane = tid & 63;
    int sub = tid >> 6;
    fill_tw256(TW, tid);
    int b  = blockIdx.x / 33;
    int c0 = (blockIdx.x - b * 33) << 2;
    int col  = c0 + sub;
    int colc = col < FREQ_COLS ? col : (FREQ_COLS - 1);
    float2* basep = Freq + ((size_t)(b * FREQ_COLS + colc) << 8);

    #pragma unroll
    for (int j = 0; j < 4; ++j) {
        int k = lane + (j << 6);
        bufB[sub][k] = basep[k];
    }
    __syncthreads();
    #pragma unroll
    for (int j = 0; j < 4; ++j) {
        int k = lane + (j << 6);
        float ax = GW[0] * bufB[sub][k].x;
        float ay = GW[0] * bufB[sub][k].y;
        #pragma unroll
        for (int t = 1; t <= 3; ++t) {
            if (k - t >= 0)  { ax += GW[t] * bufB[sub][k - t].x; ay += GW[t] * bufB[sub][k - t].y; }
            if (k + t < 256) { ax += GW[t] * bufB[sub][k + t].x; ay += GW[t] * bufB[sub][k + t].y; }
        }
        bufA[sub][k] = make_float2(ax, ay);
    }
    __syncthreads();
    fft256(bufA[sub], bufB[sub], TW, lane, -1.f);
    #pragma unroll
    for (int j = 0; j < 4; ++j) {
        int k = lane + (j << 6);
        float c = ctf[(size_t)((b << 8) | k) * FREQ_COLS + colc];
        bufA[sub][k].x *= c;
        bufA[sub][k].y *= c;
    }
    __syncthreads();
    fft256(bufA[sub], bufB[sub], TW, lane, +1.f);
    if (col < FREQ_COLS) {
        #pragma unroll
        for (int j = 0; j < 4; ++j) {
            int k = lane + (j << 6);
            basep[k] = bufA[sub][k];
        }
    }
}

// ---------------------------------------------------------------------------
// K5: Hermitian-extend + inverse row FFT + scale, 4 rows per block.
// ---------------------------------------------------------------------------
__global__ __launch_bounds__(256) void fft_rows_inv(const float2* __restrict__ Freq,
                                                    float* __restrict__ out) {
    __shared__ float2 bufA[4][256];
    __shared__ float2 bufB[4][256];
    __shared__ float2 TW[128];
    int tid = threadIdx.x;
    int lane = tid & 63;
    int sub = tid >> 6;
    fill_tw256(TW, tid);
    int b  = blockIdx.x >> 6;
    int y0 = (blockIdx.x & 63) << 2;

    for (int i = tid; i < FREQ_COLS * 4; i += 256) {
        int col = i >> 2;
        int s   = i & 3;
        bufA[s][col] = Freq[((size_t)(b * FREQ_COLS + col) << 8) + y0 + s];
    }
    __syncthreads();
    for (int k = FREQ_COLS + lane; k < 256; k += 64) {
        float2 v = bufA[sub][256 - k];
        bufA[sub][k] = make_float2(v.x, -v.y);
    }
    __syncthreads();
    fft256(bufA[sub], bufB[sub], TW, lane, +1.f);
    float* dst = out + (((size_t)(b << 8) + y0) << 8);
    const float scale = 1.0f / 65536.0f;
    for (int i = tid; i < 1024; i += 256) {
        dst[i] = bufA[i >> 8][i & 255].x * scale;
    }
}

// ---------------------------------------------------------------------------
extern "C" void kernel_launch(void* const* d_in, const int* in_sizes, int n_in,
                              void* d_out, int out_size, void* d_ws, size_t ws_size,
                              hipStream_t stream) {
    const float* rows   = (const float*)d_in[0];
    const float* shifts = (const float*)d_in[1];
    const float* latent = (const float*)d_in[2];
    const float* coords = (const float*)d_in[3];
    const float* values = (const float*)d_in[4];
    const float* W0     = (const float*)d_in[5];
    const float* b0     = (const float*)d_in[6];
    const float* W1     = (const float*)d_in[7];
    const float* b1     = (const float*)d_in[8];
    const float* W2     = (const float*)d_in[9];
    const float* b2     = (const float*)d_in[10];
    const float* W3     = (const float*)d_in[11];
    const float* b3     = (const float*)d_in[12];
    const float* Wd     = (const float*)d_in[13];
    const float* bd     = (const float*)d_in[14];
    const float* ctf    = (const float*)d_in[15];
    float* out = (float*)d_out;

    // Workspace layout
    char* w = (char*)d_ws;
    size_t off = 0;
    float* bdata = (float*)(w + off);  off += 4096;
    float* img   = (float*)(w + off);  off += (size_t)IMG_ELEMS * 4;            // 4 MB (fallback)
    float2* Freq = (float2*)(w + off); off += (size_t)BB * FREQ_COLS * 256 * 8; // 4.2 MB
    unsigned* bucket = (unsigned*)(w + off); off += (size_t)NBLK * 4096 * 4;    // 32 MB
    unsigned* lbaseT = (unsigned*)(w + off); off += (size_t)NBLK * 257 * 4;     // ~2 MB
    float* partials  = (float*)(w + off);
    size_t fixed = off;

    int M = 0;
    if      (ws_size >= fixed + 4ull * 4194304 * 4) M = 4;   // 16 MB partials
    else if (ws_size >= fixed + 2ull * 4194304)     M = 2;   // 8 MB partials

    prep_kernel<<<1, 64, 0, stream>>>(rows, shifts, latent,
                                      W0, b0, W1, b1, W2, b2, W3, b3, bdata);

    if (M > 0) {
        fill3_kernel<<<NBLK, 256, 0, stream>>>(coords, values, Wd, bd, bdata,
                                               bucket, lbaseT);
        accum2b_kernel<<<256 * M, 256, 0, stream>>>(bucket, lbaseT, partials, M);
        fft_rows_fwd<<<BB * 64, 256, 0, stream>>>(img, partials, M, Freq);
    } else {
        int n4 = IMG_ELEMS / 4;
        zero_kernel<<<(n4 + 255) / 256, 256, 0, stream>>>((float4*)img, n4);
        scatter_atomic_kernel<<<NBLK, 256, 0, stream>>>(coords, values, Wd, bd,
                                                        bdata, img);
        fft_rows_fwd<<<BB * 64, 256, 0, stream>>>(img, partials, 0, Freq);
    }

    fft_cols_ctf<<<BB * 33, 256, 0, stream>>>(Freq, ctf);
    fft_rows_inv<<<BB * 64, 256, 0, stream>>>(Freq, out);
}

// Round 8
// 164.526 us; speedup vs baseline: 2.7126x; 1.0218x over previous
//
#include <hip/hip_runtime.h>
#include <math.h>

// Problem constants (fixed by reference)
#define BB   16
#define LATD 8
#define NN   500000
#define XSZ  256
#define HALF 128
#define IMG_ELEMS (BB * XSZ * XSZ)          // 1,048,576 pixels
#define FREQ_COLS 129                        // XS/2+1
#define NBLK ((NN + 255) / 256)              // 1954 point-blocks

// Entry packing: bits[11:0] = pixel-in-tile, bits[31:12] = SIGNED 20-bit
// fixed-point value, scale 2^14. Native int LDS atomics (ds_add_u32)
// accumulate exactly; float atomicAdd = CAS retry loop (~67us pin, R0-R3).
// Global int atomics are memory-side on MI355X (non-coherent per-XCD L2):
// 8M of them wrote 249MB to HBM = 320us (R6). LDS-only atomics + the
// block-local bucket sort is the right structure.
#define QSCALE 16384.0f
#define QINV   (1.0f / 16384.0f)
__device__ __forceinline__ unsigned pack_entry_q(float v, int off12) {
    int q = (int)rintf(v * QSCALE);
    q = q >  524287 ?  524287 : q;
    q = q < -524288 ? -524288 : q;
    return ((unsigned)q << 12) | (unsigned)off12;
}
__device__ __forceinline__ int entry_q(unsigned e) {
    return ((int)e) >> 12;     // arithmetic shift: sign-extended 20-bit value
}

// ---------------------------------------------------------------------------
// wave64 inclusive scan (shuffle-based, no barriers)
// ---------------------------------------------------------------------------
__device__ __forceinline__ unsigned wave_incl_scan(unsigned x, int lane) {
    #pragma unroll
    for (int d = 1; d < 64; d <<= 1) {
        unsigned y = __shfl_up(x, d, 64);
        if (lane >= d) x += y;
    }
    return x;
}

// ---------------------------------------------------------------------------
// K0: per-image prep — rotation rows 0/1, shifts+half, SIREN MLP hidden h[8]
// ---------------------------------------------------------------------------
__global__ void prep_kernel(const float* __restrict__ rows,
                            const float* __restrict__ shifts,
                            const float* __restrict__ latent,
                            const float* __restrict__ W0, const float* __restrict__ b0,
                            const float* __restrict__ W1, const float* __restrict__ b1,
                            const float* __restrict__ W2, const float* __restrict__ b2,
                            const float* __restrict__ W3, const float* __restrict__ b3,
                            float* __restrict__ bdata) {
    int b = threadIdx.x;
    if (b >= BB) return;

    float rot  = rows[b * 3 + 0];
    float tilt = rows[b * 3 + 1];
    float psi  = rows[b * 3 + 2];
    float ca, sa, cb, sb, cg, sg;
    sincosf(rot, &sa, &ca);
    sincosf(tilt, &sb, &cb);
    sincosf(psi, &sg, &cg);

    float R00 =  cg * cb * ca - sg * sa;
    float R01 =  cg * cb * sa + sg * ca;
    float R02 = -cg * sb;
    float R10 = -sg * cb * ca - cg * sa;
    float R11 = -sg * cb * sa + cg * ca;
    float R12 =  sg * sb;

    float h[LATD], t[LATD];
    #pragma unroll
    for (int j = 0; j < LATD; ++j) {
        float acc = b0[j];
        #pragma unroll
        for (int l = 0; l < LATD; ++l) acc += latent[b * LATD + l] * W0[l * LATD + j];
        t[j] = acc;
    }
    #pragma unroll
    for (int j = 0; j < LATD; ++j) h[j] = sinf(30.0f * t[j]);

    const float* Ws[3] = {W1, W2, W3};
    const float* bs[3] = {b1, b2, b3};
    for (int L = 0; L < 3; ++L) {
        #pragma unroll
        for (int j = 0; j < LATD; ++j) {
            float acc = bs[L][j];
            #pragma unroll
            for (int l = 0; l < LATD; ++l) acc += h[l] * Ws[L][l * LATD + j];
            t[j] = acc;
        }
        #pragma unroll
        for (int j = 0; j < LATD; ++j) h[j] += sinf(t[j]);
    }

    float* P = bdata + b * 16;
    P[0] = R00; P[1] = R01; P[2] = R02;
    P[3] = R10; P[4] = R11; P[5] = R12;
    P[6] = shifts[b * 2 + 0] + (float)HALF;
    P[7] = shifts[b * 2 + 1] + (float)HALF;
    #pragma unroll
    for (int j = 0; j < LATD; ++j) P[8 + j] = h[j];
}

__device__ __forceinline__ int2 project_px(const float* __restrict__ Q,
                                           float cx, float cy, float cz) {
    float x = fmaf(Q[0], cx, fmaf(Q[1], cy, fmaf(Q[2], cz, Q[6])));
    float y = fmaf(Q[3], cx, fmaf(Q[4], cy, fmaf(Q[5], cz, Q[7])));
    float px = fminf(fmaxf(rintf(x), 0.f), 255.f);
    float py = fminf(fmaxf(rintf(y), 0.f), 255.f);
    return make_int2((int)px, (int)py);
}

// ---------------------------------------------------------------------------
// K1: fill3 — LDS-atomic ranking, per-block output: tile-sorted contiguous
// 4096-entry segment + lbaseT[blk][257] offset row. Ranking loop STAGGERS
// the image index per 16-thread group (R7, -3us: 64 lanes hit 64 distinct
// hist counters instead of 16). Arrays indexed by loop var i (static).
// ---------------------------------------------------------------------------
__global__ __launch_bounds__(256) void fill3_kernel(
        const float* __restrict__ coords, const float* __restrict__ values,
        const float* __restrict__ Wd, const float* __restrict__ bd,
        const float* __restrict__ bdata, unsigned* __restrict__ bucket,
        unsigned* __restrict__ lbaseT) {
    __shared__ float    P[256];
    __shared__ unsigned hist[256];
    __shared__ unsigned wsum[4];
    __shared__ unsigned lbase[256];
    __shared__ unsigned stage[4096];

    int tid = threadIdx.x;
    int blk = blockIdx.x;
    int lane = tid & 63;
    int w = tid >> 6;
    int grp = tid >> 4;          // 16-thread group id (stagger phase)
    P[tid] = bdata[tid];
    hist[tid] = 0;
    __syncthreads();

    int n = blk * 256 + tid;
    bool active = (n < NN);

    unsigned word[BB];
    unsigned rk[BB];
    unsigned char tl[BB];
    if (active) {
        float cx = coords[n * 3 + 0];
        float cy = coords[n * 3 + 1];
        float cz = coords[n * 3 + 2];
        float base = values[n] + bd[n];
        float wd[LATD];
        #pragma unroll
        for (int l = 0; l < LATD; ++l) wd[l] = Wd[l * NN + n];
        #pragma unroll
        for (int i = 0; i < BB; ++i) {
            int bi = (grp + i) & 15;                 // staggered image index
            const float* Q = &P[bi * 16];
            int2 p = project_px(Q, cx, cy, cz);
            float delta = 0.f;
            #pragma unroll
            for (int l = 0; l < LATD; ++l) delta = fmaf(Q[8 + l], wd[l], delta);
            int tile = bi * 16 + (p.y >> 4);
            int off12 = ((p.y & 15) << 8) | p.x;
            word[i] = pack_entry_q(base + delta, off12);
            tl[i] = (unsigned char)tile;
            rk[i] = atomicAdd(&hist[tile], 1u);
        }
    }
    __syncthreads();

    // exclusive scan of hist (256 counters) via wave shuffles
    unsigned v = hist[tid];
    unsigned s = wave_incl_scan(v, lane);
    if (lane == 63) wsum[w] = s;
    __syncthreads();
    unsigned off = 0;
    #pragma unroll
    for (int i = 0; i < 4; ++i) { unsigned u = wsum[i]; if (i < w) off += u; }
    unsigned excl = s + off - v;
    lbase[tid] = excl;
    __syncthreads();

    if (active) {
        #pragma unroll
        for (int i = 0; i < BB; ++i) {
            stage[lbase[tl[i]] + rk[i]] = word[i];
        }
    }

    int nactive = NN - blk * 256;
    if (nactive > 256) nactive = 256;
    int tot = nactive * BB;

    // offset row (coalesced): lbaseT[blk][t] = run start, [blk][256] = total
    lbaseT[(size_t)blk * 257 + tid] = excl;
    if (tid == 0) lbaseT[(size_t)blk * 257 + 256] = (unsigned)tot;
    __syncthreads();

    unsigned* seg = bucket + ((size_t)blk << 12);
    for (int i = tid; i < tot; i += 256) seg[i] = stage[i];
}

// ---------------------------------------------------------------------------
// K2: accum2b — block (t,m) accumulates tile t over a slice of source
// blocks. Bounds prefetched to LDS, 4 runs/wave, 3-deep chunk pipeline,
// 3 exec-masked slots covering runs <=48. INT fixed-point LDS atomics
// (native ds_add_u32); writeout converts to float once.
// ---------------------------------------------------------------------------
#define ACC_ISSUE(cc, S, E, Bs, X0, X1, X2) do {                            \
    int r_ = ((cc) << 4) + (w << 2) + g;                                    \
    S = 0u; E = 0u;                                                         \
    if ((cc) < nChunks && r_ < nB) { S = sArr[r_]; E = eArr[r_]; }          \
    Bs = ((size_t)(blk0 + r_) << 12);                                       \
    unsigned i0_ = S + (unsigned)sl;                                        \
    X0 = (i0_        < E) ? bucket[Bs + i0_]        : 0u;                   \
    X1 = (i0_ + 16u  < E) ? bucket[Bs + i0_ + 16u]  : 0u;                   \
    X2 = (i0_ + 32u  < E) ? bucket[Bs + i0_ + 32u]  : 0u;                   \
} while (0)

#define ACC_PROC(S, E, Bs, X0, X1, X2) do {                                 \
    unsigned i0_ = S + (unsigned)sl;                                        \
    if (i0_       < E) atomicAdd(&tile[X0 & 4095u], (unsigned)entry_q(X0)); \
    if (i0_ + 16u < E) atomicAdd(&tile[X1 & 4095u], (unsigned)entry_q(X1)); \
    if (i0_ + 32u < E) atomicAdd(&tile[X2 & 4095u], (unsigned)entry_q(X2)); \
    for (unsigned i_ = i0_ + 48u; i_ < E; i_ += 16u) {                      \
        unsigned x_ = bucket[Bs + i_];                                      \
        atomicAdd(&tile[x_ & 4095u], (unsigned)entry_q(x_));                \
    }                                                                       \
} while (0)

__global__ __launch_bounds__(256) void accum2b_kernel(
        const unsigned* __restrict__ bucket, const unsigned* __restrict__ lbaseT,
        float* __restrict__ partials, int M) {
    __shared__ unsigned tile[4096];
    __shared__ unsigned sArr[1024];   // sized for M=2 worst case (nB<=977)
    __shared__ unsigned eArr[1024];
    int t = blockIdx.x & 255;
    int m = blockIdx.x >> 8;
    int tid = threadIdx.x;
    int lane = tid & 63;
    int w = tid >> 6;
    #pragma unroll
    for (int i = 0; i < 16; ++i) tile[tid + (i << 8)] = 0u;

    int blk0 = (int)((long long)NBLK * m / M);
    int blk1 = (int)((long long)NBLK * (m + 1) / M);
    int nB = blk1 - blk0;

    // Prefetch run bounds for every source block in the slice (independent
    // loads, fully parallel; lbaseT is hot in L2 after the first readers).
    for (int r = tid; r < nB; r += 256) {
        const unsigned* lrow = lbaseT + (size_t)(blk0 + r) * 257;
        sArr[r] = lrow[t];
        eArr[r] = lrow[t + 1];   // t=255 -> slot 256 = total
    }
    __syncthreads();

    int g  = (lane >> 4);        // run group within wave: 0..3
    int sl = lane & 15;          // slot within run
    int nChunks = (nB + 15) >> 4;

    unsigned sA, eA, xA0, xA1, xA2; size_t bA;
    unsigned sB, eB, xB0, xB1, xB2; size_t bB;
    unsigned sC, eC, xC0, xC1, xC2; size_t bC;

    ACC_ISSUE(0, sA, eA, bA, xA0, xA1, xA2);
    ACC_ISSUE(1, sB, eB, bB, xB0, xB1, xB2);
    for (int c = 0; c < nChunks; c += 3) {
        ACC_ISSUE(c + 2, sC, eC, bC, xC0, xC1, xC2);
        ACC_PROC(sA, eA, bA, xA0, xA1, xA2);
        ACC_ISSUE(c + 3, sA, eA, bA, xA0, xA1, xA2);
        ACC_PROC(sB, eB, bB, xB0, xB1, xB2);
        ACC_ISSUE(c + 4, sB, eB, bB, xB0, xB1, xB2);
        ACC_PROC(sC, eC, bC, xC0, xC1, xC2);
    }
    __syncthreads();
    float* dst = partials + (((size_t)m * 256 + t) << 12);
    for (int k = tid; k < 4096; k += 256) {
        dst[k] = (float)(int)tile[k] * QINV;
    }
}

// ---------------------------------------------------------------------------
// Fallback: device-scope atomic scatter (R1 path) + zero
// ---------------------------------------------------------------------------
__global__ void zero_kernel(float4* __restrict__ p, int n4) {
    int i = blockIdx.x * blockDim.x + threadIdx.x;
    if (i < n4) p[i] = make_float4(0.f, 0.f, 0.f, 0.f);
}

__global__ __launch_bounds__(256) void scatter_atomic_kernel(
        const float* __restrict__ coords, const float* __restrict__ values,
        const float* __restrict__ Wd, const float* __restrict__ bd,
        const float* __restrict__ bdata, float* __restrict__ img) {
    __shared__ float P[BB * 16];
    P[threadIdx.x] = bdata[threadIdx.x];
    __syncthreads();
    int n = blockIdx.x * 256 + threadIdx.x;
    if (n >= NN) return;
    float cx = coords[n * 3 + 0];
    float cy = coords[n * 3 + 1];
    float cz = coords[n * 3 + 2];
    float base = values[n] + bd[n];
    float wd[LATD];
    #pragma unroll
    for (int l = 0; l < LATD; ++l) wd[l] = Wd[l * NN + n];
    #pragma unroll
    for (int b = 0; b < BB; ++b) {
        const float* Q = &P[b * 16];
        int2 p = project_px(Q, cx, cy, cz);
        float delta = 0.f;
        #pragma unroll
        for (int l = 0; l < LATD; ++l) delta = fmaf(Q[8 + l], wd[l], delta);
        atomicAdd(img + ((b << 16) | (p.y << 8) | p.x), base + delta);
    }
}

// ---------------------------------------------------------------------------
// Gaussian 7-tap weights (sigma=1, radius=3, normalized)
// ---------------------------------------------------------------------------
__device__ __constant__ float GW[4] = {0.39905027f, 0.24203623f, 0.05400558f, 0.00443305f};

// ---------------------------------------------------------------------------
// 256-point complex Stockham FFT in LDS, RADIX-4 (R8): two radix-2 stages
// fused algebraically (W^64 = i*dir factored into a swap/negate). 4 stages,
// 4 barriers, 16 LDS reads + 16 writes per lane — vs radix-2's 8 barriers
// and 32+32. Output ordering identical to the radix-2 version (derived from
// its exact stage recurrence). Ends with result in the original src buffer.
// ---------------------------------------------------------------------------
__device__ __forceinline__ void fft256(float2* src, float2* dst,
                                       const float2* __restrict__ TW,
                                       int lane, float dir) {
    #pragma unroll
    for (int st = 0; st < 4; ++st) {
        const int s = 1 << (2 * st);       // 1, 4, 16, 64
        int p = lane >> (2 * st);
        int q = lane & (s - 1);
        int base = q + s * p;              // in [0, 64)
        float2 x0 = src[base];
        float2 x1 = src[base + 64];
        float2 x2 = src[base + 128];
        float2 x3 = src[base + 192];
        int m = p * s;                     // < 64; 2m < 128
        float c1 = TW[m].x;
        float s1 = dir * TW[m].y;
        float c2 = TW[2 * m].x;
        float s2 = dir * TW[2 * m].y;

        float2 sA = make_float2(x0.x + x2.x, x0.y + x2.y);
        float2 sB = make_float2(x1.x + x3.x, x1.y + x3.y);
        float2 dAr = make_float2(x0.x - x2.x, x0.y - x2.y);
        float2 dBr = make_float2(x1.x - x3.x, x1.y - x3.y);
        // dA = dAr * W^m
        float2 dA = make_float2(dAr.x * c1 - dAr.y * s1,
                                dAr.x * s1 + dAr.y * c1);
        // dB = dBr * W^m * (i*dir)
        float2 dBt = make_float2(dBr.x * c1 - dBr.y * s1,
                                 dBr.x * s1 + dBr.y * c1);
        float2 dB = make_float2(-dir * dBt.y, dir * dBt.x);

        float2 y0 = make_float2(sA.x + sB.x, sA.y + sB.y);
        float2 y1 = make_float2(dA.x + dB.x, dA.y + dB.y);
        float2 u2 = make_float2(sA.x - sB.x, sA.y - sB.y);
        float2 u3 = make_float2(dA.x - dB.x, dA.y - dB.y);

        int o = q + 4 * s * p;
        dst[o]         = y0;
        dst[o + s]     = y1;
        dst[o + 2 * s] = make_float2(u2.x * c2 - u2.y * s2,
                                     u2.x * s2 + u2.y * c2);
        dst[o + 3 * s] = make_float2(u3.x * c2 - u3.y * s2,
                                     u3.x * s2 + u3.y * c2);
        __syncthreads();
        float2* tmp = src; src = dst; dst = tmp;
    }
}

__device__ __forceinline__ void fill_tw256(float2* TW, int tid) {
    if (tid < 128) {
        float sn, cs;
        sincosf(0.0245436926061703f * (float)tid, &sn, &cs);
        TW[tid] = make_float2(cs, sn);
    }
}

// ---------------------------------------------------------------------------
// K3: (sum M partials) + x-blur + forward row rFFT, 4 rows per block.
// ---------------------------------------------------------------------------
__global__ __launch_bounds__(256) void fft_rows_fwd(const float* __restrict__ img,
                                                    const float* __restrict__ partials,
                                                    int M,
                                                    float2* __restrict__ Freq) {
    __shared__ float2 bufA[4][256];
    __shared__ float2 bufB[4][256];
    __shared__ float2 TW[128];
    __shared__ float  rowr[4][256];
    int tid = threadIdx.x;
    int lane = tid & 63;
    int sub = tid >> 6;
    fill_tw256(TW, tid);
    int b  = blockIdx.x >> 6;
    int y0 = (blockIdx.x & 63) << 2;

    if (M > 0) {
        int t = (b << 4) | (y0 >> 4);
        const float* pb = partials + ((size_t)t << 12) + ((y0 & 15) << 8);
        const size_t mstr = (size_t)256 << 12;
        for (int i = tid; i < 1024; i += 256) {
            float s = 0.f;
            for (int m = 0; m < M; ++m) s += pb[(size_t)m * mstr + i];
            ((float*)rowr)[i] = s;
        }
    } else {
        const float* src = img + (((size_t)(b << 8) + y0) << 8);
        for (int i = tid; i < 1024; i += 256) ((float*)rowr)[i] = src[i];
    }
    __syncthreads();

    #pragma unroll
    for (int j = 0; j < 4; ++j) {
        int x = lane + (j << 6);
        float acc = GW[0] * rowr[sub][x];
        #pragma unroll
        for (int t = 1; t <= 3; ++t) {
            if (x - t >= 0)  acc += GW[t] * rowr[sub][x - t];
            if (x + t < 256) acc += GW[t] * rowr[sub][x + t];
        }
        bufA[sub][x] = make_float2(acc, 0.f);
    }
    __syncthreads();
    fft256(bufA[sub], bufB[sub], TW, lane, -1.f);

    for (int i = tid; i < FREQ_COLS * 4; i += 256) {
        int col = i >> 2;
        int s   = i & 3;
        Freq[((size_t)(b * FREQ_COLS + col) << 8) + y0 + s] = bufA[s][col];
    }
}

// ---------------------------------------------------------------------------
// K4: column pass — y-blur (complex) + FFT + CTF + inverse FFT, 4 cols/block.
// ---------------------------------------------------------------------------
__global__ __launch_bounds__(256) void fft_cols_ctf(float2* __restrict__ Freq,
                                                    const float* __restrict__ ctf) {
    __shared__ float2 bufA[4][256];
    __shared__ float2 bufB[4][256];
    __shared__ float2 TW[128];
    int tid = threadIdx.x;
    int lane = tid & 63;
    int sub = tid >> 6;
    fill_tw256(TW, tid);
    int b  = blockIdx.x / 33;
    int c0 = (blockIdx.x - b * 33) << 2;
    int col  = c0 + sub;
    int colc = col < FREQ_COLS ? col : (FREQ_COLS - 1);
    float2* basep = Freq + ((size_t)(b * FREQ_COLS + colc) << 8);

    #pragma unroll
    for (int j = 0; j < 4; ++j) {
        int k = lane + (j << 6);
        bufB[sub][k] = basep[k];
    }
    __syncthreads();
    #pragma unroll
    for (int j = 0; j < 4; ++j) {
        int k = lane + (j << 6);
        float ax = GW[0] * bufB[sub][k].x;
        float ay = GW[0] * bufB[sub][k].y;
        #pragma unroll
        for (int t = 1; t <= 3; ++t) {
            if (k - t >= 0)  { ax += GW[t] * bufB[sub][k - t].x; ay += GW[t] * bufB[sub][k - t].y; }
            if (k + t < 256) { ax += GW[t] * bufB[sub][k + t].x; ay += GW[t] * bufB[sub][k + t].y; }
        }
        bufA[sub][k] = make_float2(ax, ay);
    }
    __syncthreads();
    fft256(bufA[sub], bufB[sub], TW, lane, -1.f);
    #pragma unroll
    for (int j = 0; j < 4; ++j) {
        int k = lane + (j << 6);
        float c = ctf[(size_t)((b << 8) | k) * FREQ_COLS + colc];
        bufA[sub][k].x *= c;
        bufA[sub][k].y *= c;
    }
    __syncthreads();
    fft256(bufA[sub], bufB[sub], TW, lane, +1.f);
    if (col < FREQ_COLS) {
        #pragma unroll
        for (int j = 0; j < 4; ++j) {
            int k = lane + (j << 6);
            basep[k] = bufA[sub][k];
        }
    }
}

// ---------------------------------------------------------------------------
// K5: Hermitian-extend + inverse row FFT + scale, 4 rows per block.
// ---------------------------------------------------------------------------
__global__ __launch_bounds__(256) void fft_rows_inv(const float2* __restrict__ Freq,
                                                    float* __restrict__ out) {
    __shared__ float2 bufA[4][256];
    __shared__ float2 bufB[4][256];
    __shared__ float2 TW[128];
    int tid = threadIdx.x;
    int lane = tid & 63;
    int sub = tid >> 6;
    fill_tw256(TW, tid);
    int b  = blockIdx.x >> 6;
    int y0 = (blockIdx.x & 63) << 2;

    for (int i = tid; i < FREQ_COLS * 4; i += 256) {
        int col = i >> 2;
        int s   = i & 3;
        bufA[s][col] = Freq[((size_t)(b * FREQ_COLS + col) << 8) + y0 + s];
    }
    __syncthreads();
    for (int k = FREQ_COLS + lane; k < 256; k += 64) {
        float2 v = bufA[sub][256 - k];
        bufA[sub][k] = make_float2(v.x, -v.y);
    }
    __syncthreads();
    fft256(bufA[sub], bufB[sub], TW, lane, +1.f);
    float* dst = out + (((size_t)(b << 8) + y0) << 8);
    const float scale = 1.0f / 65536.0f;
    for (int i = tid; i < 1024; i += 256) {
        dst[i] = bufA[i >> 8][i & 255].x * scale;
    }
}

// ---------------------------------------------------------------------------
extern "C" void kernel_launch(void* const* d_in, const int* in_sizes, int n_in,
                              void* d_out, int out_size, void* d_ws, size_t ws_size,
                              hipStream_t stream) {
    const float* rows   = (const float*)d_in[0];
    const float* shifts = (const float*)d_in[1];
    const float* latent = (const float*)d_in[2];
    const float* coords = (const float*)d_in[3];
    const float* values = (const float*)d_in[4];
    const float* W0     = (const float*)d_in[5];
    const float* b0     = (const float*)d_in[6];
    const float* W1     = (const float*)d_in[7];
    const float* b1     = (const float*)d_in[8];
    const float* W2     = (const float*)d_in[9];
    const float* b2     = (const float*)d_in[10];
    const float* W3     = (const float*)d_in[11];
    const float* b3     = (const float*)d_in[12];
    const float* Wd     = (const float*)d_in[13];
    const float* bd     = (const float*)d_in[14];
    const float* ctf    = (const float*)d_in[15];
    float* out = (float*)d_out;

    // Workspace layout
    char* w = (char*)d_ws;
    size_t off = 0;
    float* bdata = (float*)(w + off);  off += 4096;
    float* img   = (float*)(w + off);  off += (size_t)IMG_ELEMS * 4;            // 4 MB (fallback)
    float2* Freq = (float2*)(w + off); off += (size_t)BB * FREQ_COLS * 256 * 8; // 4.2 MB
    unsigned* bucket = (unsigned*)(w + off); off += (size_t)NBLK * 4096 * 4;    // 32 MB
    unsigned* lbaseT = (unsigned*)(w + off); off += (size_t)NBLK * 257 * 4;     // ~2 MB
    float* partials  = (float*)(w + off);
    size_t fixed = off;

    int M = 0;
    if      (ws_size >= fixed + 4ull * 4194304 * 4) M = 4;   // 16 MB partials
    else if (ws_size >= fixed + 2ull * 4194304)     M = 2;   // 8 MB partials

    prep_kernel<<<1, 64, 0, stream>>>(rows, shifts, latent,
                                      W0, b0, W1, b1, W2, b2, W3, b3, bdata);

    if (M > 0) {
        fill3_kernel<<<NBLK, 256, 0, stream>>>(coords, values, Wd, bd, bdata,
                                               bucket, lbaseT);
        accum2b_kernel<<<256 * M, 256, 0, stream>>>(bucket, lbaseT, partials, M);
        fft_rows_fwd<<<BB * 64, 256, 0, stream>>>(img, partials, M, Freq);
    } else {
        int n4 = IMG_ELEMS / 4;
        zero_kernel<<<(n4 + 255) / 256, 256, 0, stream>>>((float4*)img, n4);
        scatter_atomic_kernel<<<NBLK, 256, 0, stream>>>(coords, values, Wd, bd,
                                                        bdata, img);
        fft_rows_fwd<<<BB * 64, 256, 0, stream>>>(img, partials, 0, Freq);
    }

    fft_cols_ctf<<<BB * 33, 256, 0, stream>>>(Freq, ctf);
    fft_rows_inv<<<BB * 64, 256, 0, stream>>>(Freq, out);
}